// Round 2
// baseline (233.177 us; speedup 1.0000x reference)
//
#include <hip/hip_runtime.h>
#include <hip/hip_cooperative_groups.h>

namespace cg = cooperative_groups;

typedef unsigned char u8;
typedef float f32x4 __attribute__((ext_vector_type(4)));
typedef float f32x16 __attribute__((ext_vector_type(16)));

#define LL 4096
#define PSTR 136              // P row stride (bytes): 2-lane/bank writes (free), validated R5
#define SCALE 16.0f           // x pre-scale before fp8
#define GSCALE (1.0f/256.0f)  // undo SCALE^2 on the gram
#define FREQC (-0.03597789207803197f)   // -ln(10000)/256

__device__ __forceinline__ long LCAST(uint2 v) { return __builtin_bit_cast(long, v); }

typedef __attribute__((address_space(3))) u8 lds_u8;
typedef __attribute__((address_space(1))) u8 glb_u8;
__device__ __forceinline__ void dma16(const u8* g, u8* l) {
  __builtin_amdgcn_global_load_lds((const glb_u8*)g, (lds_u8*)l, 16, 0, 0);
}

// ---------------- fused kernel: prep phase + grid.sync + main phase ----------------
// ONE cooperative launch (256 blocks x 512 thr, 1 block/CU, all co-resident).
// Prep phase (validated prep2 logic, bit-identical layouts):
//   xbf: row r (256 B): 8-B chunk c stored at ((c ^ (r&31))*8).
//   xT : d-row (4096 B) split into 32 j-segments of 128 B; chunk c at ((c ^ (d&15))*8).
//   Block = (batch, 64 j-rows); xT writes are contiguous 64-B half-segments.
//   T2 LDS tile aliases Kt[0] (18.4 KB < 32 KB), freed before main's prologue DMA.
// grid.sync(): device-scope release/acquire -> xbf/xT/sq visible across XCDs.
// Main phase (validated 75.5 us tpe_main, unchanged): K-tile 128, 32 iters, ONE barrier/iter,
// K dbuf LDS via global_load_lds w16, P dbuf LDS, V fragments in dbuf registers.
__global__ __launch_bounds__(512, 2) void tpe_fused(
    const float* __restrict__ x, u8* __restrict__ xbf, u8* __restrict__ xT,
    float* __restrict__ sqv, float* __restrict__ out) {
  __shared__ u8 Kt[2][32768];    // K tile 128 rows x 256 B (row-swizzled, as xbf); prep aliases T2
  __shared__ u8 Ps[2][64 * PSTR];
  __shared__ float lred[8][64];
  __shared__ float linv[64];

  const int tid = threadIdx.x;

  // ================= PREP PHASE =================
  {
    u8* T2 = Kt[0];                    // 256*72 = 18,432 B, col-major fp8: T2[d*72 + local_row]
    const int pblk = blockIdx.x;
    const int pb = pblk >> 6, ch = pblk & 63;
    const int j0 = ch << 6;            // first of this block's 64 rows
    const int wv = tid >> 6, ln = tid & 63;
    const long pbL = (long)pb * LL;
    const float4* x4 = (const float4*)x + (pbL + j0) * 64;
    unsigned* xb4 = (unsigned*)xbf + (pbL + j0) * 64;

    #pragma unroll
    for (int g = 0; g < 2; ++g) {
      int pkw[4];
      #pragma unroll
      for (int ii = 0; ii < 4; ++ii) {
        const int row = 8 * wv + 4 * g + ii;               // 0..63, wave owns 8 consecutive rows
        float4 v = x4[row * 64 + ln];                      // 1 KB contiguous per wave
        float s = v.x * v.x + v.y * v.y + v.z * v.z + v.w * v.w;
        #pragma unroll
        for (int o = 32; o; o >>= 1) s += __shfl_xor(s, o);
        if (ln == 0) sqv[pbL + j0 + row] = s;
        int pk = __builtin_amdgcn_cvt_pk_fp8_f32(v.x * SCALE, v.y * SCALE, 0, false);
        pk = __builtin_amdgcn_cvt_pk_fp8_f32(v.z * SCALE, v.w * SCALE, pk, true);
        const int sdw = (((ln >> 1) ^ ((j0 + row) & 31)) << 1) | (ln & 1);
        xb4[row * 64 + sdw] = (unsigned)pk;                // 256-B coalesced per wave
        pkw[ii] = pk;
      }
      // 4x4 byte transpose in registers (v_perm_b32), then dword writes into col-major T2.
      const int rb = 8 * wv + 4 * g;                       // first of 4 consecutive rows
      #pragma unroll
      for (int k = 0; k < 4; ++k) {
        const unsigned sel = (unsigned)(k | ((4 + k) << 8));
        unsigned m01 = __builtin_amdgcn_perm((unsigned)pkw[1], (unsigned)pkw[0], sel);
        unsigned m23 = __builtin_amdgcn_perm((unsigned)pkw[3], (unsigned)pkw[2], sel);
        unsigned tw  = __builtin_amdgcn_perm(m23, m01, 0x05040100u);
        *(unsigned*)(T2 + (4 * ln + k) * 72 + rb) = tw;    // rows rb..rb+3 at dim 4*ln+k
      }
    }
    __syncthreads();
    // Phase 2: per d-row, emit the contiguous 64-B half-segment this block owns.
    #pragma unroll
    for (int db = 0; db < 2; ++db) {
      const int d = db * 128 + (tid >> 2);
      const int oct2 = tid & 3;                            // which 16-B piece of the 64-B half
      const int key = d & 15;
      const int hb = ((ch & 1) << 3) ^ (key & 8);          // position-half base (0 or 8)
      const int p0 = hb + 2 * oct2;                        // even swizzled position
      const int c0 = (p0 ^ key) & 7;                       // local chunk (8 rows) for p0
      const int c1 = ((p0 + 1) ^ key) & 7;                 // local chunk for p0+1
      uint2 lo = *(const uint2*)(T2 + d * 72 + 8 * c0);
      uint2 hi = *(const uint2*)(T2 + d * 72 + 8 * c1);
      uint4 ov; ov.x = lo.x; ov.y = lo.y; ov.z = hi.x; ov.w = hi.y;
      // wave = 16 d-rows x 64-B contiguous bursts
      *(uint4*)(xT + (((long)(pb << 8) + d) << 12) + ((ch >> 1) << 7) + (hb << 3) + (oct2 << 4)) = ov;
    }
  }

  // device-scope release + grid barrier + acquire: xbf/xT/sq visible to all XCDs
  __threadfence();
  cg::this_grid().sync();

  // ================= MAIN PHASE =================
  const int w = tid >> 6;
  const int lane = tid & 63;
  const int l15 = lane & 15, l31 = lane & 31;
  const int q4 = lane >> 4;   // 0..3
  const int q2 = lane >> 5;   // 0..1

  // XCD pinning: batch -> XCD pair (2 MB fp8 set stays L2-hot)
  const int blk = blockIdx.x;
  const int b = (blk & 7) >> 1;
  const int qt = ((blk >> 3) << 1) | (blk & 1);
  const int q0 = qt << 6;
  const long bL = (long)b * LL;

  // Q fragments (all 64 rows, 4 chains): 64 VGPRs, from swizzled xbf
  uint2 qf[4][8];
  float qa[4];
  #pragma unroll
  for (int t = 0; t < 4; ++t) {
    const int row = q0 + 16 * t + l15;
    const u8* qrow = xbf + ((bL + row) << 8);
    const int key = row & 31;
    #pragma unroll
    for (int s = 0; s < 8; ++s)
      qf[t][s] = *(const uint2*)(qrow + (((q4 + 4 * s) ^ key) << 3));
    qa[t] = -0.5f * sqv[bL + row];
  }

  f32x16 oacc[2];
  #pragma unroll
  for (int rb = 0; rb < 2; ++rb)
    #pragma unroll
    for (int k = 0; k < 16; ++k) oacc[rb][k] = 0.f;
  float rsacc[4] = {0.f, 0.f, 0.f, 0.f};

  const u8* kbat = xbf + (bL << 8);
  // V segment base for this wave's O columns (d = 32w + l31), swizzled chunks (key = d&15)
  const u8* vseg = xT + (((long)(b << 8) + 32 * w + l31) << 12);
  const int vkey = l31 & 15;

  uint2 vfA[8], vfB[8];

  // prologue: DMA K tile 0 -> Kt[0]
  #pragma unroll
  for (int c = 0; c < 4; ++c) {
    int off = c * 8192 + tid * 16;
    dma16(kbat + off, Kt[0] + off);
  }
  __syncthreads();

#define TPE_ITER(IT, KCUR, KNXT, PPREV, PCUR, VFC, VFN)                                     \
  {                                                                                         \
    const int j0 = (IT) << 7;                                                               \
    if ((IT) < 31) { /* DMA K(it+1): full iteration of flight before the barrier drain */   \
      const u8* ks = kbat + ((long)((IT) + 1) << 15);                                       \
      _Pragma("unroll")                                                                     \
      for (int c = 0; c < 4; ++c) {                                                         \
        int off = c * 8192 + tid * 16;                                                      \
        dma16(ks + off, (KNXT) + off);                                                      \
      }                                                                                     \
    }                                                                                       \
    float4 skv4 = *(const float4*)(sqv + bL + j0 + 16 * w + 4 * q4);                        \
    if ((IT) != 0) { /* mm2 on previous tile: A = P(it-1) LDS, B = vf registers */          \
      _Pragma("unroll")                                                                     \
      for (int s = 0; s < 8; ++s) {                                                         \
        long a0 = *(const long*)((PPREV) + l31 * PSTR + 16 * s + 8 * q2);                   \
        long a1 = *(const long*)((PPREV) + (32 + l31) * PSTR + 16 * s + 8 * q2);            \
        long bv = LCAST(VFC[s]);                                                            \
        oacc[0] = __builtin_amdgcn_mfma_f32_32x32x16_fp8_fp8(a0, bv, oacc[0], 0, 0, 0);     \
        oacc[1] = __builtin_amdgcn_mfma_f32_32x32x16_fp8_fp8(a1, bv, oacc[1], 0, 0, 0);     \
      }                                                                                     \
    }                                                                                       \
    _Pragma("unroll") /* vf for THIS tile (consumed next iter, post-barrier) */             \
    for (int s = 0; s < 8; ++s)                                                             \
      VFN[s] = *(const uint2*)(vseg + j0 + (((2 * s + q2) ^ vkey) << 3));                   \
    { /* mm1: S^T = K.Q^T, 32-MFMA dense run, 4 independent chains */                       \
      const int krow = 16 * w + l15;                                                        \
      const int kkey = krow & 31;                                                           \
      const u8* kb2 = (KCUR) + krow * 256;                                                  \
      f32x4 sacc[4];                                                                        \
      _Pragma("unroll")                                                                     \
      for (int t = 0; t < 4; ++t) {                                                         \
        sacc[t][0] = 0.f; sacc[t][1] = 0.f; sacc[t][2] = 0.f; sacc[t][3] = 0.f;             \
      }                                                                                     \
      _Pragma("unroll")                                                                     \
      for (int s = 0; s < 8; ++s) {                                                         \
        uint2 kf = *(const uint2*)(kb2 + (((q4 + 4 * s) ^ kkey) << 3));                     \
        long av = LCAST(kf);                                                                \
        _Pragma("unroll")                                                                   \
        for (int t = 0; t < 4; ++t)                                                         \
          sacc[t] = __builtin_amdgcn_mfma_f32_16x16x32_fp8_fp8(av, LCAST(qf[t][s]), sacc[t], 0, 0, 0); \
      }                                                                                     \
      _Pragma("unroll") /* P = exp(min(0, g - 0.5||q||^2 - 0.5||k||^2)) -> LDS fp8 */       \
      for (int t = 0; t < 4; ++t) { /* lane: P[i=16t+l15][j=16w+4q4+0..3] */                \
        float p0 = __expf(fminf(fmaf(sacc[t][0], GSCALE, qa[t] + skv4.x), 0.f));            \
        float p1 = __expf(fminf(fmaf(sacc[t][1], GSCALE, qa[t] + skv4.y), 0.f));            \
        float p2 = __expf(fminf(fmaf(sacc[t][2], GSCALE, qa[t] + skv4.z), 0.f));            \
        float p3 = __expf(fminf(fmaf(sacc[t][3], GSCALE, qa[t] + skv4.w), 0.f));            \
        rsacc[t] += (p0 + p1) + (p2 + p3);                                                  \
        int pk = __builtin_amdgcn_cvt_pk_fp8_f32(p0, p1, 0, false);                         \
        pk = __builtin_amdgcn_cvt_pk_fp8_f32(p2, p3, pk, true);                             \
        *(int*)((PCUR) + (16 * t + l15) * PSTR + 16 * w + 4 * q4) = pk;                     \
      }                                                                                     \
    }                                                                                       \
    __syncthreads(); /* the ONLY barrier: P(it) visible, K(it+1) + vf(it) drained */        \
  }

  for (int it2 = 0; it2 < 16; ++it2) {
    TPE_ITER(2 * it2,     Kt[0], Kt[1], Ps[1], Ps[0], vfA, vfB)
    TPE_ITER(2 * it2 + 1, Kt[1], Kt[0], Ps[0], Ps[1], vfB, vfA)
  }
#undef TPE_ITER

  // ---- final mm2 (tile 31: P = Ps[1], V = vfA) ----
  #pragma unroll
  for (int s = 0; s < 8; ++s) {
    long a0 = *(const long*)(Ps[1] + l31 * PSTR + 16 * s + 8 * q2);
    long a1 = *(const long*)(Ps[1] + (32 + l31) * PSTR + 16 * s + 8 * q2);
    long bv = LCAST(vfA[s]);
    oacc[0] = __builtin_amdgcn_mfma_f32_32x32x16_fp8_fp8(a0, bv, oacc[0], 0, 0, 0);
    oacc[1] = __builtin_amdgcn_mfma_f32_32x32x16_fp8_fp8(a1, bv, oacc[1], 0, 0, 0);
  }

  // ---- epilogue: rowsum reduce; out = O/(16*l) + x + pe(inline) ----
  #pragma unroll
  for (int t = 0; t < 4; ++t) {
    float r = rsacc[t];
    r += __shfl_xor(r, 16);
    r += __shfl_xor(r, 32);
    if (lane < 16) lred[w][16 * t + l15] = r;
  }
  __syncthreads();
  if (tid < 64) {
    float s = 0.f;
    #pragma unroll
    for (int ww = 0; ww < 8; ++ww) s += lred[ww][tid];
    linv[tid] = 0.0625f / s;   // 1/16 undoes V pre-scale
  }
  __syncthreads();
  const int col = 32 * w + l31;
  const float freq = __expf((float)(col & ~1) * FREQC);
  #pragma unroll
  for (int rb = 0; rb < 2; ++rb) {
    #pragma unroll
    for (int reg = 0; reg < 16; ++reg) {
      int row = 32 * rb + 4 * q2 + (reg & 3) + 8 * (reg >> 2);
      int l = q0 + row;
      float ang = (float)l * freq;
      float pv = (col & 1) ? __cosf(ang) : __sinf(ang);
      long off = ((bL + l) << 8) + col;
      out[off] = oacc[rb][reg] * linv[row] + x[off] + pv;
    }
  }
}

extern "C" void kernel_launch(void* const* d_in, const int* in_sizes, int n_in,
                              void* d_out, int out_size, void* d_ws, size_t ws_size,
                              hipStream_t stream) {
  const float* x = (const float*)d_in[0];
  float* out = (float*)d_out;
  char* ws = (char*)d_ws;
  u8* xbf = (u8*)ws;                       // 4,194,304 B  (fp8 x, swizzled rows)
  u8* xT = (u8*)(ws + 4194304);            // 4,194,304 B  (fp8 x^T, swizzled segments)
  float* sq = (float*)(ws + 8388608);      //    65,536 B
  void* args[5] = {(void*)&x, (void*)&xbf, (void*)&xT, (void*)&sq, (void*)&out};
  hipLaunchCooperativeKernel(reinterpret_cast<void*>(tpe_fused), dim3(256), dim3(512),
                             args, 0, stream);
}

// Round 3
// 182.127 us; speedup vs baseline: 1.2803x; 1.2803x over previous
//
#include <hip/hip_runtime.h>

typedef unsigned char u8;
typedef float f32x4 __attribute__((ext_vector_type(4)));
typedef float f32x16 __attribute__((ext_vector_type(16)));

#define LL 4096
#define PSTR 72               // P row stride (bytes): 64 cols + 8 pad; 2-lane/bank (free)
#define SCALE 16.0f           // x pre-scale before fp8
#define GSCALE (1.0f/256.0f)  // undo SCALE^2 on the gram
#define FREQC (-0.03597789207803197f)   // -ln(10000)/256

__device__ __forceinline__ long LCAST(uint2 v) { return __builtin_bit_cast(long, v); }

typedef __attribute__((address_space(3))) u8 lds_u8;
typedef __attribute__((address_space(1))) u8 glb_u8;
__device__ __forceinline__ void dma16(const u8* g, u8* l) {
  __builtin_amdgcn_global_load_lds((const glb_u8*)g, (lds_u8*)l, 16, 0, 0);
}

// ---------------- prep2 (validated R1): fp8 convert + swizzled layouts, coalesced xT ----------------
//   xbf: row r (256 B): 8-B chunk c stored at ((c ^ (r&31))*8).
//   xT : d-row (4096 B) split into 32 j-segments of 128 B; chunk c at ((c ^ (d&15))*8).
__global__ __launch_bounds__(512) void prep2(const float* __restrict__ x, u8* __restrict__ xbf,
                                             u8* __restrict__ xT, float* __restrict__ sq) {
  __shared__ u8 T2[256 * 72];       // col-major fp8: T2[d*72 + local_row], 8-B pad per column
  const int blk = blockIdx.x;
  const int b = blk >> 6, ch = blk & 63;
  const int j0 = ch << 6;           // first of this block's 64 rows
  const int tid = threadIdx.x;
  const int wv = tid >> 6, ln = tid & 63;
  const long bL = (long)b * LL;
  const float4* x4 = (const float4*)x + (bL + j0) * 64;
  unsigned* xb4 = (unsigned*)xbf + (bL + j0) * 64;

  #pragma unroll
  for (int g = 0; g < 2; ++g) {
    int pkw[4];
    #pragma unroll
    for (int ii = 0; ii < 4; ++ii) {
      const int row = 8 * wv + 4 * g + ii;                 // 0..63, wave owns 8 consecutive rows
      float4 v = x4[row * 64 + ln];                        // 1 KB contiguous per wave
      float s = v.x * v.x + v.y * v.y + v.z * v.z + v.w * v.w;
      #pragma unroll
      for (int o = 32; o; o >>= 1) s += __shfl_xor(s, o);
      if (ln == 0) sq[bL + j0 + row] = s;
      int pk = __builtin_amdgcn_cvt_pk_fp8_f32(v.x * SCALE, v.y * SCALE, 0, false);
      pk = __builtin_amdgcn_cvt_pk_fp8_f32(v.z * SCALE, v.w * SCALE, pk, true);
      const int sdw = (((ln >> 1) ^ ((j0 + row) & 31)) << 1) | (ln & 1);
      xb4[row * 64 + sdw] = (unsigned)pk;                  // 256-B coalesced per wave
      pkw[ii] = pk;
    }
    // 4x4 byte transpose in registers (v_perm_b32), then dword writes into col-major T2.
    const int rb = 8 * wv + 4 * g;                         // first of 4 consecutive rows
    #pragma unroll
    for (int k = 0; k < 4; ++k) {
      const unsigned sel = (unsigned)(k | ((4 + k) << 8));
      unsigned m01 = __builtin_amdgcn_perm((unsigned)pkw[1], (unsigned)pkw[0], sel);
      unsigned m23 = __builtin_amdgcn_perm((unsigned)pkw[3], (unsigned)pkw[2], sel);
      unsigned tw  = __builtin_amdgcn_perm(m23, m01, 0x05040100u);
      *(unsigned*)(T2 + (4 * ln + k) * 72 + rb) = tw;      // rows rb..rb+3 at dim 4*ln+k
    }
  }
  __syncthreads();
  // Phase 2: per d-row, emit the contiguous 64-B half-segment this block owns.
  #pragma unroll
  for (int db = 0; db < 2; ++db) {
    const int d = db * 128 + (tid >> 2);
    const int oct2 = tid & 3;                              // which 16-B piece of the 64-B half
    const int key = d & 15;
    const int hb = ((ch & 1) << 3) ^ (key & 8);            // position-half base (0 or 8)
    const int p0 = hb + 2 * oct2;                          // even swizzled position
    const int c0 = (p0 ^ key) & 7;                         // local chunk (8 rows) for p0
    const int c1 = ((p0 + 1) ^ key) & 7;                   // local chunk for p0+1
    uint2 lo = *(const uint2*)(T2 + d * 72 + 8 * c0);
    uint2 hi = *(const uint2*)(T2 + d * 72 + 8 * c1);
    uint4 ov; ov.x = lo.x; ov.y = lo.y; ov.z = hi.x; ov.w = hi.y;
    // wave = 16 d-rows x 64-B contiguous bursts
    *(uint4*)(xT + (((long)(b << 8) + d) << 12) + ((ch >> 1) << 7) + (hb << 3) + (oct2 << 4)) = ov;
  }
}

// ---------------- main fused kernel: 2 blocks/CU convoy-breaker ----------------
// 512 blocks x 256 thr (2 blocks/CU, 4 waves each, INDEPENDENT barriers -> anti-phase
// overlap: one block's MFMA fills the other's exp/barrier bubble).
// Block = (batch, 32 Q rows). K-tile 64, 64 iters, ONE barrier/iter. Same validated
// layouts/pipeline as the 75.5us 8-wave kernel, loop bounds halved.
// mm1 (16x16x32 fp8, S^T): wave w -> j-strip 16w (0..63), 2 Q i-strips (2 chains).
// mm2 (32x32x16 fp8): wave w -> O[32][64w..64w+63] (2 d-blocks of 32).
__global__ __launch_bounds__(256, 2) void tpe_main(
    const u8* __restrict__ xbf, const u8* __restrict__ xT,
    const float* __restrict__ sqv,
    const float* __restrict__ x, float* __restrict__ out) {
  __shared__ u8 Kt[2][16384];    // K tile 64 rows x 256 B (row-swizzled, as xbf)
  __shared__ u8 Ps[2][32 * PSTR];
  __shared__ float lred[4][32];
  __shared__ float linv[32];

  const int tid = threadIdx.x;
  const int w = tid >> 6;     // 0..3
  const int lane = tid & 63;
  const int l15 = lane & 15, l31 = lane & 31;
  const int q4 = lane >> 4;   // 0..3
  const int q2 = lane >> 5;   // 0..1

  // XCD pinning: batch -> XCD pair (2 MB fp8 set stays L2-hot); 2 blocks/CU on that pair
  const int blk = blockIdx.x;
  const int b = (blk & 7) >> 1;
  const int qt = ((blk >> 3) << 1) | (blk & 1);   // 0..127
  const int q0 = qt << 5;                          // 32-row Q tile
  const long bL = (long)b * LL;

  // Q fragments (32 rows, 2 chains): 32 VGPRs, from swizzled xbf
  uint2 qf[2][8];
  float qa[2];
  #pragma unroll
  for (int t = 0; t < 2; ++t) {
    const int row = q0 + 16 * t + l15;
    const u8* qrow = xbf + ((bL + row) << 8);
    const int key = row & 31;
    #pragma unroll
    for (int s = 0; s < 8; ++s)
      qf[t][s] = *(const uint2*)(qrow + (((q4 + 4 * s) ^ key) << 3));
    qa[t] = -0.5f * sqv[bL + row];
  }

  f32x16 oacc[2];   // O[32 rows][d-block db: cols 64w+32db+l31]
  #pragma unroll
  for (int db = 0; db < 2; ++db)
    #pragma unroll
    for (int k = 0; k < 16; ++k) oacc[db][k] = 0.f;
  float rsacc[2] = {0.f, 0.f};

  const u8* kbat = xbf + (bL << 8);
  // V segment bases for this wave's two d-blocks (d = 64w + 32db + l31), key = d&15 = l31&15
  const u8* vseg0 = xT + (((long)(b << 8) + 64 * w + l31) << 12);
  const u8* vseg1 = vseg0 + (32l << 12);
  const int vkey = l31 & 15;

  uint2 vfA[2][4], vfB[2][4];

  // prologue: DMA K tile 0 -> Kt[0] (64 rows x 256 B = 16 KB)
  #pragma unroll
  for (int c = 0; c < 4; ++c) {
    int off = c * 4096 + tid * 16;
    dma16(kbat + off, Kt[0] + off);
  }
  __syncthreads();

#define TPE_ITER(IT, KCUR, KNXT, PPREV, PCUR, VFC, VFN)                                     \
  {                                                                                         \
    const int j0 = (IT) << 6;                                                               \
    if ((IT) < 63) { /* DMA K(it+1): full iteration of flight before the barrier drain */   \
      const u8* ks = kbat + ((long)((IT) + 1) << 14);                                       \
      _Pragma("unroll")                                                                     \
      for (int c = 0; c < 4; ++c) {                                                         \
        int off = c * 4096 + tid * 16;                                                      \
        dma16(ks + off, (KNXT) + off);                                                      \
      }                                                                                     \
    }                                                                                       \
    float4 skv4 = *(const float4*)(sqv + bL + j0 + 16 * w + 4 * q4);                        \
    if ((IT) != 0) { /* mm2 on previous tile: A = P(it-1) LDS, B = vf registers */          \
      _Pragma("unroll")                                                                     \
      for (int s = 0; s < 4; ++s) {                                                         \
        long a0 = *(const long*)((PPREV) + l31 * PSTR + 16 * s + 8 * q2);                   \
        oacc[0] = __builtin_amdgcn_mfma_f32_32x32x16_fp8_fp8(a0, LCAST(VFC[0][s]), oacc[0], 0, 0, 0); \
        oacc[1] = __builtin_amdgcn_mfma_f32_32x32x16_fp8_fp8(a0, LCAST(VFC[1][s]), oacc[1], 0, 0, 0); \
      }                                                                                     \
    }                                                                                       \
    { /* vf for THIS tile (consumed next iter, post-barrier); 64-j half-segment */          \
      const int segoff = ((IT) >> 1) << 7;                                                  \
      const int chb = ((IT) & 1) << 3;                                                      \
      _Pragma("unroll")                                                                     \
      for (int s = 0; s < 4; ++s) {                                                         \
        const int co = (((chb | (2 * s + q2)) ^ vkey) << 3);                                \
        VFN[0][s] = *(const uint2*)(vseg0 + segoff + co);                                   \
        VFN[1][s] = *(const uint2*)(vseg1 + segoff + co);                                   \
      }                                                                                     \
    }                                                                                       \
    { /* mm1: S^T = K.Q^T, 16-MFMA dense run, 2 independent chains */                       \
      const int krow = 16 * w + l15;                                                        \
      const int kkey = krow & 31;                                                           \
      const u8* kb2 = (KCUR) + krow * 256;                                                  \
      f32x4 sacc[2];                                                                        \
      _Pragma("unroll")                                                                     \
      for (int t = 0; t < 2; ++t) {                                                         \
        sacc[t][0] = 0.f; sacc[t][1] = 0.f; sacc[t][2] = 0.f; sacc[t][3] = 0.f;             \
      }                                                                                     \
      _Pragma("unroll")                                                                     \
      for (int s = 0; s < 8; ++s) {                                                         \
        uint2 kf = *(const uint2*)(kb2 + (((q4 + 4 * s) ^ kkey) << 3));                     \
        long av = LCAST(kf);                                                                \
        _Pragma("unroll")                                                                   \
        for (int t = 0; t < 2; ++t)                                                         \
          sacc[t] = __builtin_amdgcn_mfma_f32_16x16x32_fp8_fp8(av, LCAST(qf[t][s]), sacc[t], 0, 0, 0); \
      }                                                                                     \
      _Pragma("unroll") /* P = exp(min(0, g - 0.5||q||^2 - 0.5||k||^2)) -> LDS fp8 */       \
      for (int t = 0; t < 2; ++t) { /* lane: P[i=16t+l15][j=16w+4q4+0..3] */                \
        float p0 = __expf(fminf(fmaf(sacc[t][0], GSCALE, qa[t] + skv4.x), 0.f));            \
        float p1 = __expf(fminf(fmaf(sacc[t][1], GSCALE, qa[t] + skv4.y), 0.f));            \
        float p2 = __expf(fminf(fmaf(sacc[t][2], GSCALE, qa[t] + skv4.z), 0.f));            \
        float p3 = __expf(fminf(fmaf(sacc[t][3], GSCALE, qa[t] + skv4.w), 0.f));            \
        rsacc[t] += (p0 + p1) + (p2 + p3);                                                  \
        int pk = __builtin_amdgcn_cvt_pk_fp8_f32(p0, p1, 0, false);                         \
        pk = __builtin_amdgcn_cvt_pk_fp8_f32(p2, p3, pk, true);                             \
        *(int*)((PCUR) + (16 * t + l15) * PSTR + 16 * w + 4 * q4) = pk;                     \
      }                                                                                     \
    }                                                                                       \
    __syncthreads(); /* the ONLY barrier: P(it) visible, K(it+1) + vf(it) drained */        \
  }

  for (int it2 = 0; it2 < 32; ++it2) {
    TPE_ITER(2 * it2,     Kt[0], Kt[1], Ps[1], Ps[0], vfA, vfB)
    TPE_ITER(2 * it2 + 1, Kt[1], Kt[0], Ps[0], Ps[1], vfB, vfA)
  }
#undef TPE_ITER

  // ---- final mm2 (tile 63: P = Ps[1], V = vfA) ----
  #pragma unroll
  for (int s = 0; s < 4; ++s) {
    long a0 = *(const long*)(Ps[1] + l31 * PSTR + 16 * s + 8 * q2);
    oacc[0] = __builtin_amdgcn_mfma_f32_32x32x16_fp8_fp8(a0, LCAST(vfA[0][s]), oacc[0], 0, 0, 0);
    oacc[1] = __builtin_amdgcn_mfma_f32_32x32x16_fp8_fp8(a0, LCAST(vfA[1][s]), oacc[1], 0, 0, 0);
  }

  // ---- epilogue: rowsum reduce; out = O/(16*l) + x + pe(inline) ----
  #pragma unroll
  for (int t = 0; t < 2; ++t) {
    float r = rsacc[t];
    r += __shfl_xor(r, 16);
    r += __shfl_xor(r, 32);
    if (lane < 16) lred[w][16 * t + l15] = r;
  }
  __syncthreads();
  if (tid < 32) {
    float s = 0.f;
    #pragma unroll
    for (int ww = 0; ww < 4; ++ww) s += lred[ww][tid];
    linv[tid] = 0.0625f / s;   // 1/16 undoes V pre-scale
  }
  __syncthreads();
  #pragma unroll
  for (int db = 0; db < 2; ++db) {
    const int col = 64 * w + 32 * db + l31;
    const float freq = __expf((float)(col & ~1) * FREQC);
    #pragma unroll
    for (int reg = 0; reg < 16; ++reg) {
      int row = 4 * q2 + (reg & 3) + 8 * (reg >> 2);
      int l = q0 + row;
      float ang = (float)l * freq;
      float pv = (col & 1) ? __cosf(ang) : __sinf(ang);
      long off = ((bL + l) << 8) + col;
      out[off] = oacc[db][reg] * linv[row] + x[off] + pv;
    }
  }
}

extern "C" void kernel_launch(void* const* d_in, const int* in_sizes, int n_in,
                              void* d_out, int out_size, void* d_ws, size_t ws_size,
                              hipStream_t stream) {
  const float* x = (const float*)d_in[0];
  float* out = (float*)d_out;
  char* ws = (char*)d_ws;
  u8* xbf = (u8*)ws;                       // 4,194,304 B  (fp8 x, swizzled rows)
  u8* xT = (u8*)(ws + 4194304);            // 4,194,304 B  (fp8 x^T, swizzled segments)
  float* sq = (float*)(ws + 8388608);      //    65,536 B
  prep2<<<256, 512, 0, stream>>>(x, xbf, xT, sq);
  tpe_main<<<512, 256, 0, stream>>>(xbf, xT, sq, x, out);
}

// Round 4
// 152.269 us; speedup vs baseline: 1.5314x; 1.1961x over previous
//
#include <hip/hip_runtime.h>

typedef unsigned char u8;
typedef float f32x4 __attribute__((ext_vector_type(4)));
typedef float f32x16 __attribute__((ext_vector_type(16)));
typedef int i32x8 __attribute__((ext_vector_type(8)));

#define LL 4096
#define PSTR 136              // P row stride (bytes): 2-lane/bank reads/writes (free), validated R5
#define SCALE 16.0f           // x pre-scale before fp8
#define GSCALE (1.0f/256.0f)  // undo SCALE^2 on the gram
#define FREQC (-0.03597789207803197f)   // -ln(10000)/256
#define ONE_SC 0x7F7F7F7F     // E8M0 scale bytes = 127 -> 2^0 = 1.0 (any opsel byte)

__device__ __forceinline__ long LCAST(uint2 v) { return __builtin_bit_cast(long, v); }
__device__ __forceinline__ i32x8 PK8(uint2 a, uint2 b, uint2 c, uint2 d) {
  i32x8 r;
  r[0] = (int)a.x; r[1] = (int)a.y; r[2] = (int)b.x; r[3] = (int)b.y;
  r[4] = (int)c.x; r[5] = (int)c.y; r[6] = (int)d.x; r[7] = (int)d.y;
  return r;
}

typedef __attribute__((address_space(3))) u8 lds_u8;
typedef __attribute__((address_space(1))) u8 glb_u8;
__device__ __forceinline__ void dma16(const u8* g, u8* l) {
  __builtin_amdgcn_global_load_lds((const glb_u8*)g, (lds_u8*)l, 16, 0, 0);
}

// ---------------- prep2 (validated R1): fp8 convert + swizzled layouts, coalesced xT ----------------
//   xbf: row r (256 B): 8-B chunk c stored at ((c ^ (r&31))*8).
//   xT : d-row (4096 B) split into 32 j-segments of 128 B; chunk c at ((c ^ (d&15))*8).
__global__ __launch_bounds__(512) void prep2(const float* __restrict__ x, u8* __restrict__ xbf,
                                             u8* __restrict__ xT, float* __restrict__ sq) {
  __shared__ u8 T2[256 * 72];       // col-major fp8: T2[d*72 + local_row], 8-B pad per column
  const int blk = blockIdx.x;
  const int b = blk >> 6, ch = blk & 63;
  const int j0 = ch << 6;           // first of this block's 64 rows
  const int tid = threadIdx.x;
  const int wv = tid >> 6, ln = tid & 63;
  const long bL = (long)b * LL;
  const float4* x4 = (const float4*)x + (bL + j0) * 64;
  unsigned* xb4 = (unsigned*)xbf + (bL + j0) * 64;

  #pragma unroll
  for (int g = 0; g < 2; ++g) {
    int pkw[4];
    #pragma unroll
    for (int ii = 0; ii < 4; ++ii) {
      const int row = 8 * wv + 4 * g + ii;                 // 0..63, wave owns 8 consecutive rows
      float4 v = x4[row * 64 + ln];                        // 1 KB contiguous per wave
      float s = v.x * v.x + v.y * v.y + v.z * v.z + v.w * v.w;
      #pragma unroll
      for (int o = 32; o; o >>= 1) s += __shfl_xor(s, o);
      if (ln == 0) sq[bL + j0 + row] = s;
      int pk = __builtin_amdgcn_cvt_pk_fp8_f32(v.x * SCALE, v.y * SCALE, 0, false);
      pk = __builtin_amdgcn_cvt_pk_fp8_f32(v.z * SCALE, v.w * SCALE, pk, true);
      const int sdw = (((ln >> 1) ^ ((j0 + row) & 31)) << 1) | (ln & 1);
      xb4[row * 64 + sdw] = (unsigned)pk;                  // 256-B coalesced per wave
      pkw[ii] = pk;
    }
    // 4x4 byte transpose in registers (v_perm_b32), then dword writes into col-major T2.
    const int rb = 8 * wv + 4 * g;                         // first of 4 consecutive rows
    #pragma unroll
    for (int k = 0; k < 4; ++k) {
      const unsigned sel = (unsigned)(k | ((4 + k) << 8));
      unsigned m01 = __builtin_amdgcn_perm((unsigned)pkw[1], (unsigned)pkw[0], sel);
      unsigned m23 = __builtin_amdgcn_perm((unsigned)pkw[3], (unsigned)pkw[2], sel);
      unsigned tw  = __builtin_amdgcn_perm(m23, m01, 0x05040100u);
      *(unsigned*)(T2 + (4 * ln + k) * 72 + rb) = tw;      // rows rb..rb+3 at dim 4*ln+k
    }
  }
  __syncthreads();
  // Phase 2: per d-row, emit the contiguous 64-B half-segment this block owns.
  #pragma unroll
  for (int db = 0; db < 2; ++db) {
    const int d = db * 128 + (tid >> 2);
    const int oct2 = tid & 3;                              // which 16-B piece of the 64-B half
    const int key = d & 15;
    const int hb = ((ch & 1) << 3) ^ (key & 8);            // position-half base (0 or 8)
    const int p0 = hb + 2 * oct2;                          // even swizzled position
    const int c0 = (p0 ^ key) & 7;                         // local chunk (8 rows) for p0
    const int c1 = ((p0 + 1) ^ key) & 7;                   // local chunk for p0+1
    uint2 lo = *(const uint2*)(T2 + d * 72 + 8 * c0);
    uint2 hi = *(const uint2*)(T2 + d * 72 + 8 * c1);
    uint4 ov; ov.x = lo.x; ov.y = lo.y; ov.z = hi.x; ov.w = hi.y;
    // wave = 16 d-rows x 64-B contiguous bursts
    *(uint4*)(xT + (((long)(b << 8) + d) << 12) + ((ch >> 1) << 7) + (hb << 3) + (oct2 << 4)) = ov;
  }
}

// ---------------- main fused kernel: validated 8-wave structure + MX-scaled MFMA ----------------
// 256 blocks x 512 thr (1 block/CU, 8 waves). Block = (batch, 64 Q rows).
// K-tile 128, 32 iters, ONE barrier/iter. Same pipeline as the 75.5us kernel; ONLY the MFMA
// path changes: non-scaled fp8 -> mfma_scale_*_f8f6f4 with scale=1.0 (E8M0 127), which runs
// the fp8 pipe at ~2.1x rate with bit-equivalent arithmetic.
//   mm1: 8x mfma_scale_16x16x128 (was 32x 16x16x32). Lane-group q4 holds contiguous 32-B
//        K-span -> chunk indices 16u+4q4+i (was q4+4s stride-4 interleave). Same 8 ds_read_b64.
//   mm2: 4x mfma_scale_32x32x64 (was 16x 32x32x16). Lane-group q2 holds contiguous 32-B
//        j-span of the P row -> 4 uint2 at 64u+32q2+8i. Same 16 ds_read_b64.
//        V fragments regrouped: chunks 8u+4q2+i (same 8 global 8-B loads).
__global__ __launch_bounds__(512, 2) void tpe_main(
    const u8* __restrict__ xbf, const u8* __restrict__ xT,
    const float* __restrict__ sqv,
    const float* __restrict__ x, float* __restrict__ out) {
  __shared__ u8 Kt[2][32768];    // K tile 128 rows x 256 B (row-swizzled, as xbf)
  __shared__ u8 Ps[2][64 * PSTR];
  __shared__ float lred[8][64];
  __shared__ float linv[64];

  const int tid = threadIdx.x;
  const int w = tid >> 6;
  const int lane = tid & 63;
  const int l15 = lane & 15, l31 = lane & 31;
  const int q4 = lane >> 4;   // 0..3
  const int q2 = lane >> 5;   // 0..1

  // XCD pinning: batch -> XCD pair (2 MB fp8 set stays L2-hot)
  const int blk = blockIdx.x;
  const int b = (blk & 7) >> 1;
  const int qt = ((blk >> 3) << 1) | (blk & 1);
  const int q0 = qt << 6;
  const long bL = (long)b * LL;

  // Q fragments (all 64 rows, 4 chains), MX grouping: qmx[t][u] = K bytes [128u+32q4, +32)
  i32x8 qmx[4][2];
  float qa[4];
  #pragma unroll
  for (int t = 0; t < 4; ++t) {
    const int row = q0 + 16 * t + l15;
    const u8* qrow = xbf + ((bL + row) << 8);
    const int key = row & 31;
    #pragma unroll
    for (int u = 0; u < 2; ++u) {
      const int cb = 16 * u + 4 * q4;
      uint2 c0 = *(const uint2*)(qrow + (((cb + 0) ^ key) << 3));
      uint2 c1 = *(const uint2*)(qrow + (((cb + 1) ^ key) << 3));
      uint2 c2 = *(const uint2*)(qrow + (((cb + 2) ^ key) << 3));
      uint2 c3 = *(const uint2*)(qrow + (((cb + 3) ^ key) << 3));
      qmx[t][u] = PK8(c0, c1, c2, c3);
    }
    qa[t] = -0.5f * sqv[bL + row];
  }

  f32x16 oacc[2];
  #pragma unroll
  for (int rb = 0; rb < 2; ++rb)
    #pragma unroll
    for (int k = 0; k < 16; ++k) oacc[rb][k] = 0.f;
  float rsacc[4] = {0.f, 0.f, 0.f, 0.f};

  const u8* kbat = xbf + (bL << 8);
  // V segment base for this wave's O columns (d = 32w + l31), swizzled chunks (key = d&15)
  const u8* vseg = xT + (((long)(b << 8) + 32 * w + l31) << 12);
  const int vkey = l31 & 15;

  i32x8 vfA[2], vfB[2];

  // prologue: DMA K tile 0 -> Kt[0]
  #pragma unroll
  for (int c = 0; c < 4; ++c) {
    int off = c * 8192 + tid * 16;
    dma16(kbat + off, Kt[0] + off);
  }
  __syncthreads();

#define TPE_ITER(IT, KCUR, KNXT, PPREV, PCUR, VFC, VFN)                                     \
  {                                                                                         \
    const int j0 = (IT) << 7;                                                               \
    if ((IT) < 31) { /* DMA K(it+1): full iteration of flight before the barrier drain */   \
      const u8* ks = kbat + ((long)((IT) + 1) << 15);                                       \
      _Pragma("unroll")                                                                     \
      for (int c = 0; c < 4; ++c) {                                                         \
        int off = c * 8192 + tid * 16;                                                      \
        dma16(ks + off, (KNXT) + off);                                                      \
      }                                                                                     \
    }                                                                                       \
    float4 skv4 = *(const float4*)(sqv + bL + j0 + 16 * w + 4 * q4);                        \
    if ((IT) != 0) { /* mm2 MX on previous tile: A = P(it-1) LDS rows, B = vf registers */  \
      _Pragma("unroll")                                                                     \
      for (int u = 0; u < 2; ++u) {                                                         \
        const u8* pr0 = (PPREV) + l31 * PSTR + 64 * u + 32 * q2;                            \
        const u8* pr1 = pr0 + 32 * PSTR;                                                    \
        i32x8 pa0 = PK8(*(const uint2*)(pr0),      *(const uint2*)(pr0 + 8),                \
                        *(const uint2*)(pr0 + 16), *(const uint2*)(pr0 + 24));              \
        i32x8 pa1 = PK8(*(const uint2*)(pr1),      *(const uint2*)(pr1 + 8),                \
                        *(const uint2*)(pr1 + 16), *(const uint2*)(pr1 + 24));              \
        oacc[0] = __builtin_amdgcn_mfma_scale_f32_32x32x64_f8f6f4(                          \
            pa0, VFC[u], oacc[0], 0, 0, 0, ONE_SC, 0, ONE_SC);                              \
        oacc[1] = __builtin_amdgcn_mfma_scale_f32_32x32x64_f8f6f4(                          \
            pa1, VFC[u], oacc[1], 0, 0, 0, ONE_SC, 0, ONE_SC);                              \
      }                                                                                     \
    }                                                                                       \
    _Pragma("unroll") /* vf for THIS tile (consumed next iter, post-barrier), MX grouping */\
    for (int u = 0; u < 2; ++u) {                                                           \
      const int cb = 8 * u + 4 * q2;                                                        \
      uint2 v0 = *(const uint2*)(vseg + j0 + (((cb + 0) ^ vkey) << 3));                     \
      uint2 v1 = *(const uint2*)(vseg + j0 + (((cb + 1) ^ vkey) << 3));                     \
      uint2 v2 = *(const uint2*)(vseg + j0 + (((cb + 2) ^ vkey) << 3));                     \
      uint2 v3 = *(const uint2*)(vseg + j0 + (((cb + 3) ^ vkey) << 3));                     \
      VFN[u] = PK8(v0, v1, v2, v3);                                                         \
    }                                                                                       \
    { /* mm1 MX: S^T = K.Q^T, 8-MFMA run, 4 independent chains */                           \
      const int krow = 16 * w + l15;                                                        \
      const int kkey = krow & 31;                                                           \
      const u8* kb2 = (KCUR) + krow * 256;                                                  \
      f32x4 sacc[4];                                                                        \
      _Pragma("unroll")                                                                     \
      for (int t = 0; t < 4; ++t) {                                                         \
        sacc[t][0] = 0.f; sacc[t][1] = 0.f; sacc[t][2] = 0.f; sacc[t][3] = 0.f;             \
      }                                                                                     \
      _Pragma("unroll")                                                                     \
      for (int u = 0; u < 2; ++u) {                                                         \
        const int cb = 16 * u + 4 * q4;                                                     \
        uint2 k0 = *(const uint2*)(kb2 + (((cb + 0) ^ kkey) << 3));                         \
        uint2 k1 = *(const uint2*)(kb2 + (((cb + 1) ^ kkey) << 3));                         \
        uint2 k2 = *(const uint2*)(kb2 + (((cb + 2) ^ kkey) << 3));                         \
        uint2 k3 = *(const uint2*)(kb2 + (((cb + 3) ^ kkey) << 3));                         \
        i32x8 af = PK8(k0, k1, k2, k3);                                                     \
        _Pragma("unroll")                                                                   \
        for (int t = 0; t < 4; ++t)                                                         \
          sacc[t] = __builtin_amdgcn_mfma_scale_f32_16x16x128_f8f6f4(                       \
              af, qmx[t][u], sacc[t], 0, 0, 0, ONE_SC, 0, ONE_SC);                          \
      }                                                                                     \
      _Pragma("unroll") /* P = exp(min(0, g - 0.5||q||^2 - 0.5||k||^2)) -> LDS fp8 */       \
      for (int t = 0; t < 4; ++t) { /* lane: P[i=16t+l15][j=16w+4q4+0..3] */                \
        float p0 = __expf(fminf(fmaf(sacc[t][0], GSCALE, qa[t] + skv4.x), 0.f));            \
        float p1 = __expf(fminf(fmaf(sacc[t][1], GSCALE, qa[t] + skv4.y), 0.f));            \
        float p2 = __expf(fminf(fmaf(sacc[t][2], GSCALE, qa[t] + skv4.z), 0.f));            \
        float p3 = __expf(fminf(fmaf(sacc[t][3], GSCALE, qa[t] + skv4.w), 0.f));            \
        rsacc[t] += (p0 + p1) + (p2 + p3);                                                  \
        int pk = __builtin_amdgcn_cvt_pk_fp8_f32(p0, p1, 0, false);                         \
        pk = __builtin_amdgcn_cvt_pk_fp8_f32(p2, p3, pk, true);                             \
        *(int*)((PCUR) + (16 * t + l15) * PSTR + 16 * w + 4 * q4) = pk;                     \
      }                                                                                     \
    }                                                                                       \
    __syncthreads(); /* the ONLY barrier: P(it) visible, K(it+1) + vf(it) drained */        \
  }

  for (int it2 = 0; it2 < 16; ++it2) {
    TPE_ITER(2 * it2,     Kt[0], Kt[1], Ps[1], Ps[0], vfA, vfB)
    TPE_ITER(2 * it2 + 1, Kt[1], Kt[0], Ps[0], Ps[1], vfB, vfA)
  }
#undef TPE_ITER

  // ---- final mm2 (tile 31: P = Ps[1], V = vfA), MX form ----
  #pragma unroll
  for (int u = 0; u < 2; ++u) {
    const u8* pr0 = Ps[1] + l31 * PSTR + 64 * u + 32 * q2;
    const u8* pr1 = pr0 + 32 * PSTR;
    i32x8 pa0 = PK8(*(const uint2*)(pr0),      *(const uint2*)(pr0 + 8),
                    *(const uint2*)(pr0 + 16), *(const uint2*)(pr0 + 24));
    i32x8 pa1 = PK8(*(const uint2*)(pr1),      *(const uint2*)(pr1 + 8),
                    *(const uint2*)(pr1 + 16), *(const uint2*)(pr1 + 24));
    oacc[0] = __builtin_amdgcn_mfma_scale_f32_32x32x64_f8f6f4(
        pa0, vfA[u], oacc[0], 0, 0, 0, ONE_SC, 0, ONE_SC);
    oacc[1] = __builtin_amdgcn_mfma_scale_f32_32x32x64_f8f6f4(
        pa1, vfA[u], oacc[1], 0, 0, 0, ONE_SC, 0, ONE_SC);
  }

  // ---- epilogue: rowsum reduce; out = O/(16*l) + x + pe(inline) ----
  #pragma unroll
  for (int t = 0; t < 4; ++t) {
    float r = rsacc[t];
    r += __shfl_xor(r, 16);
    r += __shfl_xor(r, 32);
    if (lane < 16) lred[w][16 * t + l15] = r;
  }
  __syncthreads();
  if (tid < 64) {
    float s = 0.f;
    #pragma unroll
    for (int ww = 0; ww < 8; ++ww) s += lred[ww][tid];
    linv[tid] = 0.0625f / s;   // 1/16 undoes V pre-scale
  }
  __syncthreads();
  const int col = 32 * w + l31;
  const float freq = __expf((float)(col & ~1) * FREQC);
  #pragma unroll
  for (int rb = 0; rb < 2; ++rb) {
    #pragma unroll
    for (int reg = 0; reg < 16; ++reg) {
      int row = 32 * rb + 4 * q2 + (reg & 3) + 8 * (reg >> 2);
      int l = q0 + row;
      float ang = (float)l * freq;
      float pv = (col & 1) ? __cosf(ang) : __sinf(ang);
      long off = ((bL + l) << 8) + col;
      out[off] = oacc[rb][reg] * linv[row] + x[off] + pv;
    }
  }
}

extern "C" void kernel_launch(void* const* d_in, const int* in_sizes, int n_in,
                              void* d_out, int out_size, void* d_ws, size_t ws_size,
                              hipStream_t stream) {
  const float* x = (const float*)d_in[0];
  float* out = (float*)d_out;
  char* ws = (char*)d_ws;
  u8* xbf = (u8*)ws;                       // 4,194,304 B  (fp8 x, swizzled rows)
  u8* xT = (u8*)(ws + 4194304);            // 4,194,304 B  (fp8 x^T, swizzled segments)
  float* sq = (float*)(ws + 8388608);      //    65,536 B
  prep2<<<256, 512, 0, stream>>>(x, xbf, xT, sq);
  tpe_main<<<256, 512, 0, stream>>>(xbf, xT, sq, x, out);
}

// Round 5
// 123.929 us; speedup vs baseline: 1.8815x; 1.2287x over previous
//
#include <hip/hip_runtime.h>

typedef unsigned char u8;
typedef float f32x4 __attribute__((ext_vector_type(4)));
typedef float f32x16 __attribute__((ext_vector_type(16)));
typedef int i32x8 __attribute__((ext_vector_type(8)));

#define LL 4096
#define PSTR 144              // P row stride (bytes): 16-B aligned 32-B spans; writes 2-way/free
#define SCALE 16.0f           // x pre-scale before fp8
#define GSCALE (1.0f/256.0f)  // undo SCALE^2 on the gram
#define FREQC (-0.03597789207803197f)   // -ln(10000)/256
#define ONE_SC 0x7F7F7F7F     // E8M0 scale bytes = 127 -> 2^0 = 1.0

__device__ __forceinline__ i32x8 PK16(uint4 a, uint4 b) {
  i32x8 r;
  r[0] = (int)a.x; r[1] = (int)a.y; r[2] = (int)a.z; r[3] = (int)a.w;
  r[4] = (int)b.x; r[5] = (int)b.y; r[6] = (int)b.z; r[7] = (int)b.w;
  return r;
}

typedef __attribute__((address_space(3))) u8 lds_u8;
typedef __attribute__((address_space(1))) u8 glb_u8;
__device__ __forceinline__ void dma16(const u8* g, u8* l) {
  __builtin_amdgcn_global_load_lds((const glb_u8*)g, (lds_u8*)l, 16, 0, 0);
}

// ---------------- prep3: fp8 convert + 16-B-granule swizzled layouts ----------------
//   xbf: row r (256 B): 16-B chunk c stored at ((c ^ (r&15))*16).
//   xT : d-row (4096 B) = 32 j-segments of 128 B; 16-B chunk c (j 16c..16c+15) at ((c ^ (d&7))*16).
// MX fragments (32 contiguous K/j bytes per lane) load as two aligned 16-B reads directly
// into the i32x8 operand -> no register repack (R4's spill cause).
__global__ __launch_bounds__(512) void prep3(const float* __restrict__ x, u8* __restrict__ xbf,
                                             u8* __restrict__ xT, float* __restrict__ sq) {
  __shared__ u8 T2[256 * 80];       // col-major fp8: T2[d*80 + local_row], 16-B pad per column
  const int blk = blockIdx.x;
  const int b = blk >> 6, ch = blk & 63;
  const int j0 = ch << 6;           // first of this block's 64 rows
  const int tid = threadIdx.x;
  const int wv = tid >> 6, ln = tid & 63;
  const long bL = (long)b * LL;
  const float4* x4 = (const float4*)x + (bL + j0) * 64;
  unsigned* xb4 = (unsigned*)xbf + (bL + j0) * 64;

  #pragma unroll
  for (int g = 0; g < 2; ++g) {
    int pkw[4];
    #pragma unroll
    for (int ii = 0; ii < 4; ++ii) {
      const int row = 8 * wv + 4 * g + ii;                 // 0..63, wave owns 8 consecutive rows
      float4 v = x4[row * 64 + ln];                        // 1 KB contiguous per wave
      float s = v.x * v.x + v.y * v.y + v.z * v.z + v.w * v.w;
      #pragma unroll
      for (int o = 32; o; o >>= 1) s += __shfl_xor(s, o);
      if (ln == 0) sq[bL + j0 + row] = s;
      int pk = __builtin_amdgcn_cvt_pk_fp8_f32(v.x * SCALE, v.y * SCALE, 0, false);
      pk = __builtin_amdgcn_cvt_pk_fp8_f32(v.z * SCALE, v.w * SCALE, pk, true);
      // 16-B granule swizzle: dword ln belongs to chunk16 (ln>>2); position = chunk ^ (row&15)
      const int sdw = ((((ln >> 2) ^ ((j0 + row) & 15)) << 2)) | (ln & 3);
      xb4[row * 64 + sdw] = (unsigned)pk;                  // 256-B coalesced per wave
      pkw[ii] = pk;
    }
    // 4x4 byte transpose in registers (v_perm_b32), then dword writes into col-major T2.
    const int rb = 8 * wv + 4 * g;                         // first of 4 consecutive rows
    #pragma unroll
    for (int k = 0; k < 4; ++k) {
      const unsigned sel = (unsigned)(k | ((4 + k) << 8));
      unsigned m01 = __builtin_amdgcn_perm((unsigned)pkw[1], (unsigned)pkw[0], sel);
      unsigned m23 = __builtin_amdgcn_perm((unsigned)pkw[3], (unsigned)pkw[2], sel);
      unsigned tw  = __builtin_amdgcn_perm(m23, m01, 0x05040100u);
      *(unsigned*)(T2 + (4 * ln + k) * 80 + rb) = tw;      // rows rb..rb+3 at dim 4*ln+k
    }
  }
  __syncthreads();
  // Phase 2: per d-row, emit this block's 4 16-B chunks (one 64-B contiguous burst per d).
  #pragma unroll
  for (int db = 0; db < 2; ++db) {
    const int d = db * 128 + (tid >> 2);
    const int cl = tid & 3;                                // local chunk16 (16 local rows)
    const int c16 = ((ch & 1) << 2) | cl;                  // global chunk16 within segment
    const int p = c16 ^ (d & 7);                           // swizzled position
    uint4 ov = *(const uint4*)(T2 + d * 80 + 16 * cl);     // 16 consecutive local rows at dim d
    *(uint4*)(xT + (((long)(b << 8) + d) << 12) + ((ch >> 1) << 7) + (p << 4)) = ov;
  }
}

// ---------------- main fused kernel: 8-wave structure + MX MFMA, load-direct fragments ----------------
// 256 blocks x 512 thr (1 block/CU, 8 waves). Block = (batch, 64 Q rows).
// K-tile 128, 32 iters, ONE barrier/iter. Identical pipeline to the validated 75.5us kernel;
// MFMA path = mfma_scale (scale=1.0, bit-equivalent, ~2.1x rate). All MX operands are
// 32 contiguous K/j bytes per lane = 2 aligned 16-B loads straight into the i32x8 tuple.
//   mm1: 4x ds_read_b128 + 8x mfma_scale_16x16x128 (4 chains x 2).
//   mm2: 8x ds_read_b128 + 4x mfma_scale_32x32x64.
//   vf : 4x global dwordx4 (prefetched pre-barrier, consumed next iter).
__global__ __launch_bounds__(512, 2) void tpe_main(
    const u8* __restrict__ xbf, const u8* __restrict__ xT,
    const float* __restrict__ sqv,
    const float* __restrict__ x, float* __restrict__ out) {
  __shared__ __align__(16) u8 Kt[2][32768];    // K tile 128 rows x 256 B (16-B-granule swizzled)
  __shared__ __align__(16) u8 Ps[2][64 * PSTR];
  __shared__ float lred[8][64];
  __shared__ float linv[64];

  const int tid = threadIdx.x;
  const int w = tid >> 6;
  const int lane = tid & 63;
  const int l15 = lane & 15, l31 = lane & 31;
  const int q4 = lane >> 4;   // 0..3
  const int q2 = lane >> 5;   // 0..1

  // XCD pinning: batch -> XCD pair (2 MB fp8 set stays L2-hot)
  const int blk = blockIdx.x;
  const int b = (blk & 7) >> 1;
  const int qt = ((blk >> 3) << 1) | (blk & 1);
  const int q0 = qt << 6;
  const long bL = (long)b * LL;

  // Q fragments (all 64 rows, 4 chains), MX grouping: qmx[t][u] = K bytes [128u+32q4, +32)
  // row & 15 == l15 for all Q/K rows (q0, 16t multiples of 16) -> swizzle key is l15.
  i32x8 qmx[4][2];
  float qa[4];
  #pragma unroll
  for (int t = 0; t < 4; ++t) {
    const int row = q0 + 16 * t + l15;
    const u8* qrow = xbf + ((bL + row) << 8);
    #pragma unroll
    for (int u = 0; u < 2; ++u) {
      const int cb = 8 * u + 2 * q4;
      uint4 lo = *(const uint4*)(qrow + (((cb + 0) ^ l15) << 4));
      uint4 hi = *(const uint4*)(qrow + (((cb + 1) ^ l15) << 4));
      qmx[t][u] = PK16(lo, hi);
    }
    qa[t] = -0.5f * sqv[bL + row];
  }

  f32x16 oacc[2];
  #pragma unroll
  for (int rb = 0; rb < 2; ++rb)
    #pragma unroll
    for (int k = 0; k < 16; ++k) oacc[rb][k] = 0.f;
  float rsacc[4] = {0.f, 0.f, 0.f, 0.f};

  const u8* kbat = xbf + (bL << 8);
  // V segment base for this wave's O columns (d = 32w + l31), 16-B chunks keyed by d&7
  const u8* vseg = xT + (((long)(b << 8) + 32 * w + l31) << 12);
  const int vk7 = l31 & 7;

  i32x8 vfA[2], vfB[2];

  // prologue: DMA K tile 0 -> Kt[0]
  #pragma unroll
  for (int c = 0; c < 4; ++c) {
    int off = c * 8192 + tid * 16;
    dma16(kbat + off, Kt[0] + off);
  }
  __syncthreads();

#define TPE_ITER(IT, KCUR, KNXT, PPREV, PCUR, VFC, VFN)                                     \
  {                                                                                         \
    const int j0 = (IT) << 7;                                                               \
    if ((IT) < 31) { /* DMA K(it+1): full iteration of flight before the barrier drain */   \
      const u8* ks = kbat + ((long)((IT) + 1) << 15);                                       \
      _Pragma("unroll")                                                                     \
      for (int c = 0; c < 4; ++c) {                                                         \
        int off = c * 8192 + tid * 16;                                                      \
        dma16(ks + off, (KNXT) + off);                                                      \
      }                                                                                     \
    }                                                                                       \
    float4 skv4 = *(const float4*)(sqv + bL + j0 + 16 * w + 4 * q4);                        \
    if ((IT) != 0) { /* mm2 MX on previous tile: A = P(it-1) rows (2x b128), B = vf regs */ \
      _Pragma("unroll")                                                                     \
      for (int u = 0; u < 2; ++u) {                                                         \
        const u8* pr0 = (PPREV) + l31 * PSTR + 64 * u + 32 * q2;                            \
        i32x8 pa0 = PK16(*(const uint4*)(pr0), *(const uint4*)(pr0 + 16));                  \
        i32x8 pa1 = PK16(*(const uint4*)(pr0 + 32 * PSTR),                                  \
                         *(const uint4*)(pr0 + 32 * PSTR + 16));                            \
        oacc[0] = __builtin_amdgcn_mfma_scale_f32_32x32x64_f8f6f4(                          \
            pa0, VFC[u], oacc[0], 0, 0, 0, ONE_SC, 0, ONE_SC);                              \
        oacc[1] = __builtin_amdgcn_mfma_scale_f32_32x32x64_f8f6f4(                          \
            pa1, VFC[u], oacc[1], 0, 0, 0, ONE_SC, 0, ONE_SC);                              \
      }                                                                                     \
    }                                                                                       \
    _Pragma("unroll") /* vf for THIS tile (consumed next iter, post-barrier) */             \
    for (int u = 0; u < 2; ++u) {                                                           \
      const int cb = 4 * u + 2 * q2;                                                        \
      uint4 v0 = *(const uint4*)(vseg + j0 + (((cb + 0) ^ vk7) << 4));                      \
      uint4 v1 = *(const uint4*)(vseg + j0 + (((cb + 1) ^ vk7) << 4));                      \
      VFN[u] = PK16(v0, v1);                                                                \
    }                                                                                       \
    { /* mm1 MX: S^T = K.Q^T, 8-MFMA run, 4 independent chains */                           \
      const int krow = 16 * w + l15;                                                        \
      const u8* kb2 = (KCUR) + krow * 256;                                                  \
      f32x4 sacc[4];                                                                        \
      _Pragma("unroll")                                                                     \
      for (int t = 0; t < 4; ++t) {                                                         \
        sacc[t][0] = 0.f; sacc[t][1] = 0.f; sacc[t][2] = 0.f; sacc[t][3] = 0.f;             \
      }                                                                                     \
      _Pragma("unroll")                                                                     \
      for (int u = 0; u < 2; ++u) {                                                         \
        const int cb = 8 * u + 2 * q4;                                                      \
        uint4 klo = *(const uint4*)(kb2 + (((cb + 0) ^ l15) << 4));                         \
        uint4 khi = *(const uint4*)(kb2 + (((cb + 1) ^ l15) << 4));                         \
        i32x8 af = PK16(klo, khi);                                                          \
        _Pragma("unroll")                                                                   \
        for (int t = 0; t < 4; ++t)                                                         \
          sacc[t] = __builtin_amdgcn_mfma_scale_f32_16x16x128_f8f6f4(                       \
              af, qmx[t][u], sacc[t], 0, 0, 0, ONE_SC, 0, ONE_SC);                          \
      }                                                                                     \
      _Pragma("unroll") /* P = exp(min(0, g - 0.5||q||^2 - 0.5||k||^2)) -> LDS fp8 */       \
      for (int t = 0; t < 4; ++t) { /* lane: P[i=16t+l15][j=16w+4q4+0..3] */                \
        float p0 = __expf(fminf(fmaf(sacc[t][0], GSCALE, qa[t] + skv4.x), 0.f));            \
        float p1 = __expf(fminf(fmaf(sacc[t][1], GSCALE, qa[t] + skv4.y), 0.f));            \
        float p2 = __expf(fminf(fmaf(sacc[t][2], GSCALE, qa[t] + skv4.z), 0.f));            \
        float p3 = __expf(fminf(fmaf(sacc[t][3], GSCALE, qa[t] + skv4.w), 0.f));            \
        rsacc[t] += (p0 + p1) + (p2 + p3);                                                  \
        int pk = __builtin_amdgcn_cvt_pk_fp8_f32(p0, p1, 0, false);                         \
        pk = __builtin_amdgcn_cvt_pk_fp8_f32(p2, p3, pk, true);                             \
        *(int*)((PCUR) + (16 * t + l15) * PSTR + 16 * w + 4 * q4) = pk;                     \
      }                                                                                     \
    }                                                                                       \
    __syncthreads(); /* the ONLY barrier: P(it) visible, K(it+1) + vf(it) drained */        \
  }

  for (int it2 = 0; it2 < 16; ++it2) {
    TPE_ITER(2 * it2,     Kt[0], Kt[1], Ps[1], Ps[0], vfA, vfB)
    TPE_ITER(2 * it2 + 1, Kt[1], Kt[0], Ps[0], Ps[1], vfB, vfA)
  }
#undef TPE_ITER

  // ---- final mm2 (tile 31: P = Ps[1], V = vfA), MX form ----
  #pragma unroll
  for (int u = 0; u < 2; ++u) {
    const u8* pr0 = Ps[1] + l31 * PSTR + 64 * u + 32 * q2;
    i32x8 pa0 = PK16(*(const uint4*)(pr0), *(const uint4*)(pr0 + 16));
    i32x8 pa1 = PK16(*(const uint4*)(pr0 + 32 * PSTR), *(const uint4*)(pr0 + 32 * PSTR + 16));
    oacc[0] = __builtin_amdgcn_mfma_scale_f32_32x32x64_f8f6f4(
        pa0, vfA[u], oacc[0], 0, 0, 0, ONE_SC, 0, ONE_SC);
    oacc[1] = __builtin_amdgcn_mfma_scale_f32_32x32x64_f8f6f4(
        pa1, vfA[u], oacc[1], 0, 0, 0, ONE_SC, 0, ONE_SC);
  }

  // ---- epilogue: rowsum reduce; out = O/(16*l) + x + pe(inline) ----
  #pragma unroll
  for (int t = 0; t < 4; ++t) {
    float r = rsacc[t];
    r += __shfl_xor(r, 16);
    r += __shfl_xor(r, 32);
    if (lane < 16) lred[w][16 * t + l15] = r;
  }
  __syncthreads();
  if (tid < 64) {
    float s = 0.f;
    #pragma unroll
    for (int ww = 0; ww < 8; ++ww) s += lred[ww][tid];
    linv[tid] = 0.0625f / s;   // 1/16 undoes V pre-scale
  }
  __syncthreads();
  const int col = 32 * w + l31;
  const float freq = __expf((float)(col & ~1) * FREQC);
  #pragma unroll
  for (int rb = 0; rb < 2; ++rb) {
    #pragma unroll
    for (int reg = 0; reg < 16; ++reg) {
      int row = 32 * rb + 4 * q2 + (reg & 3) + 8 * (reg >> 2);
      int l = q0 + row;
      float ang = (float)l * freq;
      float pv = (col & 1) ? __cosf(ang) : __sinf(ang);
      long off = ((bL + l) << 8) + col;
      out[off] = oacc[rb][reg] * linv[row] + x[off] + pv;
    }
  }
}

extern "C" void kernel_launch(void* const* d_in, const int* in_sizes, int n_in,
                              void* d_out, int out_size, void* d_ws, size_t ws_size,
                              hipStream_t stream) {
  const float* x = (const float*)d_in[0];
  float* out = (float*)d_out;
  char* ws = (char*)d_ws;
  u8* xbf = (u8*)ws;                       // 4,194,304 B  (fp8 x, 16-B-granule swizzled rows)
  u8* xT = (u8*)(ws + 4194304);            // 4,194,304 B  (fp8 x^T, 16-B-granule swizzled segments)
  float* sq = (float*)(ws + 8388608);      //    65,536 B
  prep3<<<256, 512, 0, stream>>>(x, xbf, xT, sq);
  tpe_main<<<256, 512, 0, stream>>>(xbf, xT, sq, x, out);
}